// Round 1
// baseline (6004.025 us; speedup 1.0000x reference)
//
#include <hip/hip_runtime.h>
#include <math.h>

typedef unsigned short u16;
typedef unsigned int   u32;

#define NSIDE  240
#define NPIX   57600
#define DMODEL 256
#define NHEAD  8
#define HDIM   32
#define LWIN   20
#define NWIN   12
#define FF     400
#define DFFN   2048
#define BTAB   39   // 2*LW-1

// ---- ws layout (bytes) ----
#define OFF_QKVW 0u           // 768*256 bf16   = 393216
#define OFF_OUTW 393216u      // 256*256 bf16   = 131072
#define OFF_W1   524288u      // 2048*256 bf16  = 1048576
#define OFF_W2   1572864u     // 256*2048 bf16  = 1048576
#define OFF_FLAG 2621440u     // int flag (mask dtype)
#define OFF_NM   2621952u     // normalized mask 57600 B
#define OFF_A    2679808u     // region A: 256*57600 bf16 = 29491200 (src2 / attnout / ln2out)
#define OFF_B    32171008u    // region B: 768*57600 bf16 = 88473600 (qkv, later x1 f32)

__device__ __forceinline__ float bf2f(u16 u){
  union { float f; u32 i; } v; v.i = ((u32)u) << 16; return v.f;
}
__device__ __forceinline__ float bflo(u32 u){
  union { float f; u32 i; } v; v.i = u << 16; return v.f;
}
__device__ __forceinline__ float bfhi(u32 u){
  union { float f; u32 i; } v; v.i = u & 0xffff0000u; return v.f;
}
__device__ __forceinline__ u16 f2bf(float f){
  union { float f; u32 i; } v; v.f = f;
  u32 r = v.i + 0x7fffu + ((v.i >> 16) & 1u);
  return (u16)(r >> 16);
}

// ---------------- prep: f32 -> bf16 weight convert ----------------
__global__ void cvt_kernel(const float* __restrict__ in, u16* __restrict__ out, int n){
  int i = blockIdx.x * 256 + threadIdx.x;
  if (i < n) out[i] = f2bf(in[i]);
}

// ---------------- mask dtype detect + normalize ----------------
// True mask is pad(i)|pad(j): symmetric in (i,j). If bytes-view is asymmetric,
// the buffer must be int32-encoded bool; otherwise treat as 1-byte bool.
__global__ void detect_mask(const unsigned char* __restrict__ m, int* __restrict__ flag){
  __shared__ int sc;
  if (threadIdx.x == 0) sc = 0;
  __syncthreads();
  int local = 0;
  for (int p = threadIdx.x; p < NPIX; p += blockDim.x){
    int i = p / NSIDE, j = p - i * NSIDE;
    int pt = j * NSIDE + i;
    int a = (m[p] != 0), b = (m[pt] != 0);
    local += (a != b);
  }
  atomicAdd(&sc, local);
  __syncthreads();
  if (threadIdx.x == 0) *flag = (sc > 0) ? 1 : 0;
}
__global__ void norm_mask(const void* __restrict__ m, const int* __restrict__ flag,
                          unsigned char* __restrict__ nm){
  int p = blockIdx.x * 256 + threadIdx.x;
  int v;
  if (*flag) v = (((const int*)m)[p] != 0);
  else       v = (((const unsigned char*)m)[p] != 0);
  nm[p] = (unsigned char)v;
}

// ---------------- LayerNorm over channels ----------------
// x: [256][NPIX] f32 (channel-major), out: [256][NPIX] bf16
__global__ __launch_bounds__(256) void ln_kernel(const float* __restrict__ x,
                          const float* __restrict__ g, const float* __restrict__ b,
                          u16* __restrict__ out){
  int p = blockIdx.x * 256 + threadIdx.x;
  float s = 0.f, s2 = 0.f;
  for (int c = 0; c < DMODEL; c++){
    float v = x[c * NPIX + p];
    s += v; s2 += v * v;
  }
  float m = s * (1.f / DMODEL);
  float var = s2 * (1.f / DMODEL) - m * m;
  float inv = rsqrtf(var + 1e-5f);
  for (int c = 0; c < DMODEL; c++){
    float v = (x[c * NPIX + p] - m) * inv * g[c] + b[c];
    out[c * NPIX + p] = f2bf(v);
  }
}

// ---------------- GEMM: C[M][NPIX] = W[M][K] * X[K][NPIX] ----------------
// EPI 0: +bias -> bf16 out; EPI 1: +bias + residual(f32) -> f32 out
template<int EPI>
__global__ __launch_bounds__(256) void gemm_kernel(const u16* __restrict__ W, const u16* __restrict__ X,
                            const float* __restrict__ bias, const float* __restrict__ res,
                            void* __restrict__ outp, int M, int K){
  __shared__ u16 Wt[64 * 34];   // padded stride 34 (bank spread)
  __shared__ u16 Xt[32 * 64];
  int t = threadIdx.x;
  int n0 = blockIdx.x * 64;
  int m0 = blockIdx.y * 64;
  int tr = t >> 4, tc = t & 15;
  float acc[4][4] = {};
  for (int k0 = 0; k0 < K; k0 += 32){
    {
      int row = t >> 2, col = (t & 3) * 8;
      uint4 gv = *(const uint4*)&W[(m0 + row) * K + k0 + col];
      u32* d = (u32*)&Wt[row * 34 + col];
      d[0] = gv.x; d[1] = gv.y; d[2] = gv.z; d[3] = gv.w;
      int row2 = t >> 3, col2 = (t & 7) * 8;
      uint4 gx = *(const uint4*)&X[(k0 + row2) * NPIX + n0 + col2];
      *(uint4*)&Xt[row2 * 64 + col2] = gx;
    }
    __syncthreads();
    #pragma unroll
    for (int kk = 0; kk < 32; kk += 2){
      float aA[4][2];
      #pragma unroll
      for (int r = 0; r < 4; r++){
        u32 ad = *(const u32*)&Wt[(tr * 4 + r) * 34 + kk];
        aA[r][0] = bflo(ad); aA[r][1] = bfhi(ad);
      }
      float bB[2][4];
      #pragma unroll
      for (int hh = 0; hh < 2; hh++){
        u32 b0 = *(const u32*)&Xt[(kk + hh) * 64 + tc * 4];
        u32 b1 = *(const u32*)&Xt[(kk + hh) * 64 + tc * 4 + 2];
        bB[hh][0] = bflo(b0); bB[hh][1] = bfhi(b0);
        bB[hh][2] = bflo(b1); bB[hh][3] = bfhi(b1);
      }
      #pragma unroll
      for (int r = 0; r < 4; r++)
        #pragma unroll
        for (int c = 0; c < 4; c++)
          acc[r][c] += aA[r][0] * bB[0][c] + aA[r][1] * bB[1][c];
    }
    __syncthreads();
  }
  #pragma unroll
  for (int r = 0; r < 4; r++){
    int mo = m0 + tr * 4 + r;
    float bv = bias[mo];
    #pragma unroll
    for (int c = 0; c < 4; c++){
      int no = n0 + tc * 4 + c;
      float v = acc[r][c] + bv;
      if (EPI == 0) ((u16*)outp)[mo * NPIX + no] = f2bf(v);
      else          ((float*)outp)[mo * NPIX + no] = v + res[mo * NPIX + no];
    }
  }
}

// ---------------- windowed attention: one block per (window, head) ----------------
__global__ __launch_bounds__(256) void attn_kernel(const u16* __restrict__ qkv, const float* __restrict__ relb,
                            const unsigned char* __restrict__ pmask, u16* __restrict__ out){
  __shared__ u16 ks[HDIM * FF];         // [d][j]
  __shared__ u16 vs[HDIM * FF];
  __shared__ float bs[BTAB * BTAB];
  __shared__ unsigned char mks[FF];
  __shared__ int cnt;
  int w = blockIdx.x, h = blockIdx.y;
  int wi = w / NWIN, wj = w % NWIN;
  int t = threadIdx.x;
  if (t == 0) cnt = 0;
  __syncthreads();
  for (int j = t; j < FF; j += 256){
    int pj = (wi * LWIN + j / LWIN) * NSIDE + wj * LWIN + (j % LWIN);
    int mv = pmask[pj] ? 1 : 0;
    mks[j] = (unsigned char)mv;
    if (mv) atomicAdd(&cnt, 1);
  }
  int kbase = (DMODEL + h * HDIM) * NPIX;
  int vbase = (2 * DMODEL + h * HDIM) * NPIX;
  for (int e = t; e < HDIM * FF; e += 256){
    int d = e / FF, j = e - d * FF;
    int pj = (wi * LWIN + j / LWIN) * NSIDE + wj * LWIN + (j % LWIN);
    ks[e] = qkv[kbase + d * NPIX + pj];
    vs[e] = qkv[vbase + d * NPIX + pj];
  }
  for (int e = t; e < BTAB * BTAB; e += 256) bs[e] = relb[e * NHEAD + h];
  __syncthreads();
  bool anymask = (cnt != 0) && (cnt != FF);   // full window -> mask reset (all attend)
  const float scaling = 0.1767766952966369f;  // 32^-0.5
  for (int ib = 0; ib < 2; ib++){
    int i = ib * 256 + t;
    if (i >= FF) break;
    int xi = i / LWIN, yi = i - xi * LWIN;
    int pi = (wi * LWIN + xi) * NSIDE + wj * LWIN + yi;
    float q[HDIM];
    #pragma unroll
    for (int d = 0; d < HDIM; d++)
      q[d] = bf2f(qkv[(h * HDIM + d) * NPIX + pi]) * scaling;
    // pass 1: online max / sum
    float mx = -1e30f, l = 0.f;
    for (int j = 0; j < FF; j += 2){
      float d0 = 0.f, d1 = 0.f;
      #pragma unroll
      for (int d = 0; d < HDIM; d++){
        u32 kv = *(const u32*)&ks[d * FF + j];
        d0 += q[d] * bflo(kv);
        d1 += q[d] * bfhi(kv);
      }
      int xj = j / LWIN, yj = j - xj * LWIN;
      {
        int r0 = xj - xi; r0 += (r0 < 0) ? BTAB : 0;
        int r1 = yj - yi; r1 += (r1 < 0) ? BTAB : 0;
        float s = d0 + bs[r0 * BTAB + r1];
        if (!(anymask && mks[j])){
          if (s <= mx) l += __expf(s - mx);
          else { l = l * __expf(mx - s) + 1.f; mx = s; }
        }
      }
      {
        int yj1 = yj + 1, xj1 = xj;
        if (yj1 == LWIN){ yj1 = 0; xj1++; }
        int r0 = xj1 - xi; r0 += (r0 < 0) ? BTAB : 0;
        int r1 = yj1 - yi; r1 += (r1 < 0) ? BTAB : 0;
        float s = d1 + bs[r0 * BTAB + r1];
        if (!(anymask && mks[j + 1])){
          if (s <= mx) l += __expf(s - mx);
          else { l = l * __expf(mx - s) + 1.f; mx = s; }
        }
      }
    }
    float linv = 1.f / l;
    // pass 2: probabilities * V
    float acc[HDIM] = {};
    for (int j = 0; j < FF; j += 2){
      float d0 = 0.f, d1 = 0.f;
      #pragma unroll
      for (int d = 0; d < HDIM; d++){
        u32 kv = *(const u32*)&ks[d * FF + j];
        d0 += q[d] * bflo(kv);
        d1 += q[d] * bfhi(kv);
      }
      int xj = j / LWIN, yj = j - xj * LWIN;
      float p0 = 0.f, p1 = 0.f;
      {
        int r0 = xj - xi; r0 += (r0 < 0) ? BTAB : 0;
        int r1 = yj - yi; r1 += (r1 < 0) ? BTAB : 0;
        float s = d0 + bs[r0 * BTAB + r1];
        if (!(anymask && mks[j])) p0 = __expf(s - mx);
      }
      {
        int yj1 = yj + 1, xj1 = xj;
        if (yj1 == LWIN){ yj1 = 0; xj1++; }
        int r0 = xj1 - xi; r0 += (r0 < 0) ? BTAB : 0;
        int r1 = yj1 - yi; r1 += (r1 < 0) ? BTAB : 0;
        float s = d1 + bs[r0 * BTAB + r1];
        if (!(anymask && mks[j + 1])) p1 = __expf(s - mx);
      }
      #pragma unroll
      for (int d = 0; d < HDIM; d++){
        u32 vv = *(const u32*)&vs[d * FF + j];
        acc[d] += p0 * bflo(vv) + p1 * bfhi(vv);
      }
    }
    #pragma unroll
    for (int d = 0; d < HDIM; d++)
      out[(h * HDIM + d) * NPIX + pi] = f2bf(acc[d] * linv);
  }
}

// ---------------- fused FFN: lin2(relu(lin1(xn))) + residual, final zero-mask ----------------
#define FFN_PT 64
#define FFN_FC 32
__global__ __launch_bounds__(256) void ffn_kernel(const u16* __restrict__ xn, const u16* __restrict__ w1,
                           const u16* __restrict__ w2, const float* __restrict__ b1,
                           const float* __restrict__ b2, const float* __restrict__ resid,
                           const unsigned char* __restrict__ pmask, float* __restrict__ out){
  __shared__ u16 xs[DMODEL * FFN_PT];   // 32768 B  [c][p]
  __shared__ u16 wstage[8704];          // 17408 B: w1 chunk [32][256] OR w2 chunk [256][34]
  __shared__ float hs[FFN_FC * FFN_PT]; // 8192 B   [f][p]
  int t = threadIdx.x;
  int p0 = blockIdx.x * FFN_PT;
  for (int it = 0; it < 8; it++){
    int e = (t + it * 256) * 8;
    int row = e >> 6, col = e & 63;
    uint4 gv = *(const uint4*)&xn[row * NPIX + p0 + col];
    *(uint4*)&xs[row * 64 + col] = gv;
  }
  int ogB = t >> 4, pgB = t & 15;
  int fgA = t >> 5, pgA = t & 31;
  float acc[16][4] = {};
  for (int fc = 0; fc < DFFN / FFN_FC; fc++){
    __syncthreads();  // previous phase B done before overwriting wstage (also covers xs stage on fc==0)
    for (int it = 0; it < 4; it++){
      int e = (t + it * 256) * 8;
      int row = e >> 8, col = e & 255;
      uint4 gv = *(const uint4*)&w1[(fc * FFN_FC + row) * DMODEL + col];
      *(uint4*)&wstage[row * 256 + col] = gv;
    }
    __syncthreads();
    // phase A: h[f][p] = relu(b1 + W1 x), thread tile 4f x 2p
    float ha[4][2];
    #pragma unroll
    for (int ff = 0; ff < 4; ff++){
      float bv = b1[fc * FFN_FC + fgA * 4 + ff];
      ha[ff][0] = bv; ha[ff][1] = bv;
    }
    for (int c = 0; c < DMODEL; c += 2){
      u32 xd0 = *(const u32*)&xs[c * 64 + pgA * 2];
      u32 xd1 = *(const u32*)&xs[(c + 1) * 64 + pgA * 2];
      float x00 = bflo(xd0), x01 = bfhi(xd0);
      float x10 = bflo(xd1), x11 = bfhi(xd1);
      #pragma unroll
      for (int ff = 0; ff < 4; ff++){
        u32 wd = *(const u32*)&wstage[(fgA * 4 + ff) * 256 + c];
        float wv0 = bflo(wd), wv1 = bfhi(wd);
        ha[ff][0] += wv0 * x00 + wv1 * x10;
        ha[ff][1] += wv0 * x01 + wv1 * x11;
      }
    }
    #pragma unroll
    for (int ff = 0; ff < 4; ff++){
      hs[(fgA * 4 + ff) * 64 + pgA * 2]     = fmaxf(ha[ff][0], 0.f);
      hs[(fgA * 4 + ff) * 64 + pgA * 2 + 1] = fmaxf(ha[ff][1], 0.f);
    }
    __syncthreads();
    for (int it = 0; it < 4; it++){
      int e = (t + it * 256) * 8;
      int row = e >> 5, col = e & 31;
      uint4 gv = *(const uint4*)&w2[row * DFFN + fc * FFN_FC + col];
      u32* dst = (u32*)&wstage[row * 34 + col];
      dst[0] = gv.x; dst[1] = gv.y; dst[2] = gv.z; dst[3] = gv.w;
    }
    __syncthreads();
    // phase B: acc[o][p] += W2 h, thread tile 16o x 4p
    for (int fp = 0; fp < FFN_FC / 2; fp++){
      int f = fp * 2;
      float4 hv0 = *(const float4*)&hs[f * 64 + pgB * 4];
      float4 hv1 = *(const float4*)&hs[(f + 1) * 64 + pgB * 4];
      #pragma unroll
      for (int oo = 0; oo < 16; oo++){
        u32 wd = *(const u32*)&wstage[(ogB * 16 + oo) * 34 + f];
        float w20 = bflo(wd), w21 = bfhi(wd);
        acc[oo][0] += w20 * hv0.x + w21 * hv1.x;
        acc[oo][1] += w20 * hv0.y + w21 * hv1.y;
        acc[oo][2] += w20 * hv0.z + w21 * hv1.z;
        acc[oo][3] += w20 * hv0.w + w21 * hv1.w;
      }
    }
  }
  #pragma unroll
  for (int oo = 0; oo < 16; oo++){
    int o = ogB * 16 + oo;
    float bv = b2[o];
    #pragma unroll
    for (int pp = 0; pp < 4; pp++){
      int p = p0 + pgB * 4 + pp;
      float v = acc[oo][pp] + bv + resid[o * NPIX + p];
      out[o * NPIX + p] = pmask[p] ? 0.f : v;
    }
  }
}

extern "C" void kernel_launch(void* const* d_in, const int* in_sizes, int n_in,
                              void* d_out, int out_size, void* d_ws, size_t ws_size,
                              hipStream_t stream){
  const float* src    = (const float*)d_in[0];
  const void*  pmraw  = d_in[1];
  const float* qkv_w  = (const float*)d_in[2];
  const float* qkv_b  = (const float*)d_in[3];
  const float* out_w  = (const float*)d_in[4];
  const float* out_b  = (const float*)d_in[5];
  const float* lin1_w = (const float*)d_in[6];
  const float* lin1_b = (const float*)d_in[7];
  const float* lin2_w = (const float*)d_in[8];
  const float* lin2_b = (const float*)d_in[9];
  const float* n1_g   = (const float*)d_in[10];
  const float* n1_b   = (const float*)d_in[11];
  const float* n2_g   = (const float*)d_in[12];
  const float* n2_b   = (const float*)d_in[13];
  const float* relb   = (const float*)d_in[14];

  char* ws = (char*)d_ws;
  u16* qkvw_bf = (u16*)(ws + OFF_QKVW);
  u16* outw_bf = (u16*)(ws + OFF_OUTW);
  u16* w1_bf   = (u16*)(ws + OFF_W1);
  u16* w2_bf   = (u16*)(ws + OFF_W2);
  int* flag    = (int*)(ws + OFF_FLAG);
  unsigned char* nm = (unsigned char*)(ws + OFF_NM);
  u16* bufA    = (u16*)(ws + OFF_A);   // src2 -> attnout -> ln2out
  u16* qkvbuf  = (u16*)(ws + OFF_B);   // qkv bf16
  float* x1    = (float*)(ws + OFF_B); // later: residual stream f32 (qkv dead)

  // prep
  cvt_kernel<<<768,  256, 0, stream>>>(qkv_w,  qkvw_bf, 768 * 256);
  cvt_kernel<<<256,  256, 0, stream>>>(out_w,  outw_bf, 256 * 256);
  cvt_kernel<<<2048, 256, 0, stream>>>(lin1_w, w1_bf,   2048 * 256);
  cvt_kernel<<<2048, 256, 0, stream>>>(lin2_w, w2_bf,   256 * 2048);
  detect_mask<<<1, 256, 0, stream>>>((const unsigned char*)pmraw, flag);
  norm_mask<<<225, 256, 0, stream>>>(pmraw, flag, nm);

  // 1) LN1 -> src2 (bufA)
  ln_kernel<<<225, 256, 0, stream>>>(src, n1_g, n1_b, bufA);
  // 2) qkv = W_qkv * src2 + b  -> qkvbuf (bufB)
  gemm_kernel<0><<<dim3(900, 12), 256, 0, stream>>>(qkvw_bf, bufA, qkv_b, nullptr,
                                                    (void*)qkvbuf, 768, 256);
  // 3) windowed attention -> attnout (bufA, src2 dead)
  attn_kernel<<<dim3(144, 8), 256, 0, stream>>>(qkvbuf, relb, nm, bufA);
  // 4) out conv + residual -> x1 f32 (bufB, qkv dead)
  gemm_kernel<1><<<dim3(900, 4), 256, 0, stream>>>(outw_bf, bufA, out_b, src,
                                                   (void*)x1, 256, 256);
  // 5) LN2 -> ln2out (bufA, attnout dead)
  ln_kernel<<<225, 256, 0, stream>>>(x1, n2_g, n2_b, bufA);
  // 6) fused FFN + residual + final mask -> d_out
  ffn_kernel<<<900, 256, 0, stream>>>(bufA, w1_bf, w2_bf, lin1_b, lin2_b, x1, nm,
                                      (float*)d_out);
}

// Round 2
// 2436.461 us; speedup vs baseline: 2.4642x; 2.4642x over previous
//
#include <hip/hip_runtime.h>
#include <math.h>

typedef unsigned short u16;
typedef unsigned int   u32;
typedef __attribute__((ext_vector_type(8))) short bf16x8;
typedef __attribute__((ext_vector_type(4))) float f32x4;

#define NSIDE  240
#define NPIX   57600
#define DMODEL 256
#define NHEAD  8
#define HDIM   32
#define LWIN   20
#define NWIN   12
#define FF     400
#define DFFN   2048
#define BTAB   39   // 2*LW-1

// ---- ws layout (bytes) ----
#define OFF_QKVW 0u           // 768*256 bf16 (swizzled)
#define OFF_OUTW 393216u      // 256*256 bf16 (swizzled)
#define OFF_W1   524288u      // 2048*256 bf16 (plain)
#define OFF_W2   1572864u     // 256*2048 bf16 (plain)
#define OFF_FLAG 2621440u
#define OFF_NM   2621952u
#define OFF_A    2679808u     // region A: 57600*256 bf16 (X^T swizzled: ln1out/attnout/ln2out)
#define OFF_B    32171008u    // region B: qkv bf16 [768][NPIX]; later x1 f32 [256][NPIX]

__device__ __forceinline__ float bf2f(u16 u){
  union { float f; u32 i; } v; v.i = ((u32)u) << 16; return v.f;
}
__device__ __forceinline__ float bflo(u32 u){
  union { float f; u32 i; } v; v.i = u << 16; return v.f;
}
__device__ __forceinline__ float bfhi(u32 u){
  union { float f; u32 i; } v; v.i = u & 0xffff0000u; return v.f;
}
__device__ __forceinline__ u16 f2bf(float f){
  union { float f; u32 i; } v; v.f = f;
  u32 r = v.i + 0x7fffu + ((v.i >> 16) & 1u);
  return (u16)(r >> 16);
}
__device__ __forceinline__ void gload16(const void* g, void* l){
  __builtin_amdgcn_global_load_lds((const __attribute__((address_space(1))) u32*)g,
                                   (__attribute__((address_space(3))) u32*)l, 16, 0, 0);
}

// ---------------- prep: f32 -> bf16 weight converts ----------------
__global__ void cvt_kernel(const float* __restrict__ in, u16* __restrict__ out, int n){
  int i = blockIdx.x * 256 + threadIdx.x;
  if (i < n) out[i] = f2bf(in[i]);
}
// swizzled variant for K=256 row-major weights: elem k stored at k ^ ((m&7)<<3)
__global__ void cvt_sw_kernel(const float* __restrict__ in, u16* __restrict__ out, int n){
  int i = blockIdx.x * 256 + threadIdx.x;
  if (i >= n) return;
  int m = i >> 8, k = i & 255;
  out[(m << 8) + (k ^ ((m & 7) << 3))] = f2bf(in[i]);
}

// ---------------- mask dtype detect + normalize ----------------
__global__ void detect_mask(const unsigned char* __restrict__ m, int* __restrict__ flag){
  __shared__ int sc;
  if (threadIdx.x == 0) sc = 0;
  __syncthreads();
  int local = 0;
  for (int p = threadIdx.x; p < NPIX; p += blockDim.x){
    int i = p / NSIDE, j = p - i * NSIDE;
    int pt = j * NSIDE + i;
    int a = (m[p] != 0), b = (m[pt] != 0);
    local += (a != b);
  }
  atomicAdd(&sc, local);
  __syncthreads();
  if (threadIdx.x == 0) *flag = (sc > 0) ? 1 : 0;
}
__global__ void norm_mask(const void* __restrict__ m, const int* __restrict__ flag,
                          unsigned char* __restrict__ nm){
  int p = blockIdx.x * 256 + threadIdx.x;
  int v;
  if (*flag) v = (((const int*)m)[p] != 0);
  else       v = (((const unsigned char*)m)[p] != 0);
  nm[p] = (unsigned char)v;
}

// ---------------- LayerNorm over channels -> X^T [NPIX][256] bf16, swizzled ----------------
__global__ __launch_bounds__(256) void ln_kernel(const float* __restrict__ x,
                          const float* __restrict__ g, const float* __restrict__ b,
                          u16* __restrict__ out){
  int p = blockIdx.x * 256 + threadIdx.x;
  float s = 0.f, s2 = 0.f;
  for (int c = 0; c < DMODEL; c++){
    float v = x[c * NPIX + p];
    s += v; s2 += v * v;
  }
  float m = s * (1.f / DMODEL);
  float var = s2 * (1.f / DMODEL) - m * m;
  float inv = rsqrtf(var + 1e-5f);
  int sw = (p & 7) << 3;
  u16* orow = out + (size_t)p * DMODEL;
  for (int c = 0; c < DMODEL; c += 2){
    float v0 = (x[c * NPIX + p] - m) * inv * g[c] + b[c];
    float v1 = (x[(c + 1) * NPIX + p] - m) * inv * g[c + 1] + b[c + 1];
    u32 pk = (u32)f2bf(v0) | ((u32)f2bf(v1) << 16);
    *(u32*)&orow[c ^ sw] = pk;   // c even, sw on bits 3..5 -> stays u32-aligned
  }
}

// ---------------- MFMA GEMM: C[M][NPIX] = W[M][256] * Xt[NPIX][256]^T ----------------
// W, Xt both bf16 row-major, pre-swizzled (elem k at k ^ ((row&7)<<3)).
// EPI 0: +bias -> bf16 [M][NPIX]; EPI 1: +bias+res -> f32 [M][NPIX]
template<int EPI>
__global__ __launch_bounds__(256) void gemm_nt(const u16* __restrict__ W,
    const u16* __restrict__ Xt, const float* __restrict__ bias,
    const float* __restrict__ res, void* __restrict__ outp, int M){
  __shared__ u16 Ws[128 * 64];
  __shared__ u16 Xs[128 * 64];
  int t = threadIdx.x, wv = t >> 6, ln = t & 63;
  int n0 = blockIdx.x * 128, m0 = blockIdx.y * 128;
  int wr = wv >> 1, wc = wv & 1;
  f32x4 acc[4][4];
  #pragma unroll
  for (int r = 0; r < 4; r++)
    #pragma unroll
    for (int c = 0; c < 4; c++) acc[r][c] = (f32x4)0.f;
  const char* Wb = (const char*)W;
  const char* Xb = (const char*)Xt;
  for (int k0 = 0; k0 < 256; k0 += 64){
    #pragma unroll
    for (int i = 0; i < 4; i++){
      int wb = (wv * 4 + i) * 1024;
      int q  = wb + ln * 16;
      int row = q >> 7, off = q & 127;
      gload16(Wb + (size_t)(m0 + row) * 512 + k0 * 2 + off, (char*)Ws + wb);
      gload16(Xb + (size_t)(n0 + row) * 512 + k0 * 2 + off, (char*)Xs + wb);
    }
    __syncthreads();
    #pragma unroll
    for (int kk = 0; kk < 64; kk += 32){
      int kidx = kk + (ln >> 4) * 8;
      int swz = (ln & 7) << 3;
      bf16x8 af[4], bfr[4];
      #pragma unroll
      for (int r = 0; r < 4; r++){
        int row = wr * 64 + r * 16 + (ln & 15);
        af[r] = *(const bf16x8*)&Ws[row * 64 + (kidx ^ swz)];
      }
      #pragma unroll
      for (int c = 0; c < 4; c++){
        int row = wc * 64 + c * 16 + (ln & 15);
        bfr[c] = *(const bf16x8*)&Xs[row * 64 + (kidx ^ swz)];
      }
      #pragma unroll
      for (int r = 0; r < 4; r++)
        #pragma unroll
        for (int c = 0; c < 4; c++)
          acc[r][c] = __builtin_amdgcn_mfma_f32_16x16x32_bf16(af[r], bfr[c], acc[r][c], 0, 0, 0);
    }
    __syncthreads();
  }
  #pragma unroll
  for (int r = 0; r < 4; r++){
    int mo0 = m0 + wr * 64 + r * 16 + (ln >> 4) * 4;
    f32x4 bv = *(const f32x4*)&bias[mo0];
    #pragma unroll
    for (int c = 0; c < 4; c++){
      int no = n0 + wc * 64 + c * 16 + (ln & 15);
      #pragma unroll
      for (int q = 0; q < 4; q++){
        float v = acc[r][c][q] + bv[q];
        size_t oi = (size_t)(mo0 + q) * NPIX + no;
        if (EPI == 0) ((u16*)outp)[oi] = f2bf(v);
        else          ((float*)outp)[oi] = v + res[oi];
      }
    }
  }
}

// ---------------- windowed attention (unchanged math; X^T swizzled output) ----------------
__global__ __launch_bounds__(256) void attn_kernel(const u16* __restrict__ qkv, const float* __restrict__ relb,
                            const unsigned char* __restrict__ pmask, u16* __restrict__ out){
  __shared__ u16 ks[HDIM * FF];
  __shared__ u16 vs[HDIM * FF];
  __shared__ float bs[BTAB * BTAB];
  __shared__ unsigned char mks[FF];
  __shared__ int cnt;
  int w = blockIdx.x, h = blockIdx.y;
  int wi = w / NWIN, wj = w % NWIN;
  int t = threadIdx.x;
  if (t == 0) cnt = 0;
  __syncthreads();
  for (int j = t; j < FF; j += 256){
    int pj = (wi * LWIN + j / LWIN) * NSIDE + wj * LWIN + (j % LWIN);
    int mv = pmask[pj] ? 1 : 0;
    mks[j] = (unsigned char)mv;
    if (mv) atomicAdd(&cnt, 1);
  }
  int kbase = (DMODEL + h * HDIM) * NPIX;
  int vbase = (2 * DMODEL + h * HDIM) * NPIX;
  for (int e = t; e < HDIM * FF; e += 256){
    int d = e / FF, j = e - d * FF;
    int pj = (wi * LWIN + j / LWIN) * NSIDE + wj * LWIN + (j % LWIN);
    ks[e] = qkv[kbase + d * NPIX + pj];
    vs[e] = qkv[vbase + d * NPIX + pj];
  }
  for (int e = t; e < BTAB * BTAB; e += 256) bs[e] = relb[e * NHEAD + h];
  __syncthreads();
  bool anymask = (cnt != 0) && (cnt != FF);
  const float scaling = 0.1767766952966369f;
  for (int ib = 0; ib < 2; ib++){
    int i = ib * 256 + t;
    if (i >= FF) break;
    int xi = i / LWIN, yi = i - xi * LWIN;
    int pi = (wi * LWIN + xi) * NSIDE + wj * LWIN + yi;
    float q[HDIM];
    #pragma unroll
    for (int d = 0; d < HDIM; d++)
      q[d] = bf2f(qkv[(h * HDIM + d) * NPIX + pi]) * scaling;
    float mx = -1e30f, l = 0.f;
    for (int j = 0; j < FF; j += 2){
      float d0 = 0.f, d1 = 0.f;
      #pragma unroll
      for (int d = 0; d < HDIM; d++){
        u32 kv = *(const u32*)&ks[d * FF + j];
        d0 += q[d] * bflo(kv);
        d1 += q[d] * bfhi(kv);
      }
      int xj = j / LWIN, yj = j - xj * LWIN;
      {
        int r0 = xj - xi; r0 += (r0 < 0) ? BTAB : 0;
        int r1 = yj - yi; r1 += (r1 < 0) ? BTAB : 0;
        float s = d0 + bs[r0 * BTAB + r1];
        if (!(anymask && mks[j])){
          if (s <= mx) l += __expf(s - mx);
          else { l = l * __expf(mx - s) + 1.f; mx = s; }
        }
      }
      {
        int yj1 = yj + 1, xj1 = xj;
        if (yj1 == LWIN){ yj1 = 0; xj1++; }
        int r0 = xj1 - xi; r0 += (r0 < 0) ? BTAB : 0;
        int r1 = yj1 - yi; r1 += (r1 < 0) ? BTAB : 0;
        float s = d1 + bs[r0 * BTAB + r1];
        if (!(anymask && mks[j + 1])){
          if (s <= mx) l += __expf(s - mx);
          else { l = l * __expf(mx - s) + 1.f; mx = s; }
        }
      }
    }
    float linv = 1.f / l;
    float acc[HDIM] = {};
    for (int j = 0; j < FF; j += 2){
      float d0 = 0.f, d1 = 0.f;
      #pragma unroll
      for (int d = 0; d < HDIM; d++){
        u32 kv = *(const u32*)&ks[d * FF + j];
        d0 += q[d] * bflo(kv);
        d1 += q[d] * bfhi(kv);
      }
      int xj = j / LWIN, yj = j - xj * LWIN;
      float p0 = 0.f, p1 = 0.f;
      {
        int r0 = xj - xi; r0 += (r0 < 0) ? BTAB : 0;
        int r1 = yj - yi; r1 += (r1 < 0) ? BTAB : 0;
        float s = d0 + bs[r0 * BTAB + r1];
        if (!(anymask && mks[j])) p0 = __expf(s - mx);
      }
      {
        int yj1 = yj + 1, xj1 = xj;
        if (yj1 == LWIN){ yj1 = 0; xj1++; }
        int r0 = xj1 - xi; r0 += (r0 < 0) ? BTAB : 0;
        int r1 = yj1 - yi; r1 += (r1 < 0) ? BTAB : 0;
        float s = d1 + bs[r0 * BTAB + r1];
        if (!(anymask && mks[j + 1])) p1 = __expf(s - mx);
      }
      #pragma unroll
      for (int d = 0; d < HDIM; d++){
        u32 vv = *(const u32*)&vs[d * FF + j];
        acc[d] += p0 * bflo(vv) + p1 * bfhi(vv);
      }
    }
    // write A^T [NPIX][256] bf16, swizzled like LN output
    int swo = (pi & 7) << 3;
    u16* orow = out + (size_t)pi * DMODEL;
    #pragma unroll
    for (int d = 0; d < HDIM; d += 2){
      u32 pk = (u32)f2bf(acc[d] * linv) | ((u32)f2bf(acc[d + 1] * linv) << 16);
      *(u32*)&orow[(h * HDIM + d) ^ swo] = pk;
    }
  }
}

// ---------------- fused FFN (MFMA): out = mask0(resid + b2 + W2*relu(b1 + W1*xn)) ----------------
__global__ __launch_bounds__(256) void ffn_kernel(const u16* __restrict__ xt,
    const u16* __restrict__ w1, const u16* __restrict__ w2,
    const float* __restrict__ b1, const float* __restrict__ b2,
    const float* __restrict__ resid, const unsigned char* __restrict__ pmask,
    float* __restrict__ out){
  __shared__ u16 Xs[64 * 256];   // X^T panel, rows swizzled as stored
  __shared__ u16 Hs[64 * 72];    // H^T [p][f], +16B pad -> conflict-free
  int t = threadIdx.x, wv = t >> 6, ln = t & 63;
  int p0 = blockIdx.x * 64;
  const char* xb = (const char*)xt + (size_t)p0 * 512;
  #pragma unroll
  for (int i = 0; i < 8; i++){
    int wb = (wv * 8 + i) * 1024;
    gload16(xb + wb + ln * 16, (char*)Xs + wb);
  }
  f32x4 acc[4][4];
  #pragma unroll
  for (int r = 0; r < 4; r++)
    #pragma unroll
    for (int c = 0; c < 4; c++) acc[r][c] = (f32x4)0.f;
  int swx = (ln & 7) << 3;
  __syncthreads();
  for (int fc = 0; fc < DFFN; fc += 64){
    // phase A: H[f=fc+wv*16+..][p] = relu(b1 + W1 . X)
    f32x4 ha[4];
    #pragma unroll
    for (int c = 0; c < 4; c++) ha[c] = (f32x4)0.f;
    const u16* w1r = w1 + (size_t)(fc + wv * 16 + (ln & 15)) * 256 + (ln >> 4) * 8;
    #pragma unroll
    for (int k0 = 0; k0 < 256; k0 += 32){
      bf16x8 aw = *(const bf16x8*)&w1r[k0];
      #pragma unroll
      for (int c = 0; c < 4; c++){
        int p = c * 16 + (ln & 15);
        bf16x8 bx = *(const bf16x8*)&Xs[p * 256 + ((k0 + (ln >> 4) * 8) ^ swx)];
        ha[c] = __builtin_amdgcn_mfma_f32_16x16x32_bf16(aw, bx, ha[c], 0, 0, 0);
      }
    }
    int f0 = wv * 16 + (ln >> 4) * 4;
    f32x4 bv1 = *(const f32x4*)&b1[fc + f0];
    #pragma unroll
    for (int c = 0; c < 4; c++){
      int p = c * 16 + (ln & 15);
      float r0 = fmaxf(ha[c][0] + bv1[0], 0.f);
      float r1 = fmaxf(ha[c][1] + bv1[1], 0.f);
      float r2 = fmaxf(ha[c][2] + bv1[2], 0.f);
      float r3 = fmaxf(ha[c][3] + bv1[3], 0.f);
      uint2 pk;
      pk.x = (u32)f2bf(r0) | ((u32)f2bf(r1) << 16);
      pk.y = (u32)f2bf(r2) | ((u32)f2bf(r3) << 16);
      *(uint2*)&Hs[p * 72 + f0] = pk;
    }
    __syncthreads();
    // phase B: acc[o][p] += W2[:, fc..fc+64] . H
    #pragma unroll
    for (int kk = 0; kk < 64; kk += 32){
      int fi = kk + (ln >> 4) * 8;
      bf16x8 a2[4], hb[4];
      #pragma unroll
      for (int r = 0; r < 4; r++)
        a2[r] = *(const bf16x8*)&w2[(size_t)(wv * 64 + r * 16 + (ln & 15)) * 2048 + fc + fi];
      #pragma unroll
      for (int c = 0; c < 4; c++)
        hb[c] = *(const bf16x8*)&Hs[(c * 16 + (ln & 15)) * 72 + fi];
      #pragma unroll
      for (int r = 0; r < 4; r++)
        #pragma unroll
        for (int c = 0; c < 4; c++)
          acc[r][c] = __builtin_amdgcn_mfma_f32_16x16x32_bf16(a2[r], hb[c], acc[r][c], 0, 0, 0);
    }
    __syncthreads();
  }
  #pragma unroll
  for (int r = 0; r < 4; r++){
    int o0 = wv * 64 + r * 16 + (ln >> 4) * 4;
    f32x4 bv = *(const f32x4*)&b2[o0];
    #pragma unroll
    for (int c = 0; c < 4; c++){
      int p = p0 + c * 16 + (ln & 15);
      int msk = pmask[p];
      #pragma unroll
      for (int q = 0; q < 4; q++){
        size_t oi = (size_t)(o0 + q) * NPIX + p;
        float v = acc[r][c][q] + bv[q] + resid[oi];
        out[oi] = msk ? 0.f : v;
      }
    }
  }
}

extern "C" void kernel_launch(void* const* d_in, const int* in_sizes, int n_in,
                              void* d_out, int out_size, void* d_ws, size_t ws_size,
                              hipStream_t stream){
  const float* src    = (const float*)d_in[0];
  const void*  pmraw  = d_in[1];
  const float* qkv_w  = (const float*)d_in[2];
  const float* qkv_b  = (const float*)d_in[3];
  const float* out_w  = (const float*)d_in[4];
  const float* out_b  = (const float*)d_in[5];
  const float* lin1_w = (const float*)d_in[6];
  const float* lin1_b = (const float*)d_in[7];
  const float* lin2_w = (const float*)d_in[8];
  const float* lin2_b = (const float*)d_in[9];
  const float* n1_g   = (const float*)d_in[10];
  const float* n1_b   = (const float*)d_in[11];
  const float* n2_g   = (const float*)d_in[12];
  const float* n2_b   = (const float*)d_in[13];
  const float* relb   = (const float*)d_in[14];

  char* ws = (char*)d_ws;
  u16* qkvw_bf = (u16*)(ws + OFF_QKVW);
  u16* outw_bf = (u16*)(ws + OFF_OUTW);
  u16* w1_bf   = (u16*)(ws + OFF_W1);
  u16* w2_bf   = (u16*)(ws + OFF_W2);
  int* flag    = (int*)(ws + OFF_FLAG);
  unsigned char* nm = (unsigned char*)(ws + OFF_NM);
  u16* bufA    = (u16*)(ws + OFF_A);   // X^T swizzled: ln1out -> attnout -> ln2out
  u16* qkvbuf  = (u16*)(ws + OFF_B);   // qkv bf16 [768][NPIX]
  float* x1    = (float*)(ws + OFF_B); // residual stream f32 (qkv dead)

  // prep
  cvt_sw_kernel<<<768,  256, 0, stream>>>(qkv_w,  qkvw_bf, 768 * 256);
  cvt_sw_kernel<<<256,  256, 0, stream>>>(out_w,  outw_bf, 256 * 256);
  cvt_kernel<<<2048, 256, 0, stream>>>(lin1_w, w1_bf, 2048 * 256);
  cvt_kernel<<<2048, 256, 0, stream>>>(lin2_w, w2_bf, 256 * 2048);
  detect_mask<<<1, 256, 0, stream>>>((const unsigned char*)pmraw, flag);
  norm_mask<<<225, 256, 0, stream>>>(pmraw, flag, nm);

  // 1) LN1 -> X^T swizzled (bufA)
  ln_kernel<<<225, 256, 0, stream>>>(src, n1_g, n1_b, bufA);
  // 2) qkv = W_qkv . X^T' + b  -> [768][NPIX] bf16
  gemm_nt<0><<<dim3(450, 6), 256, 0, stream>>>(qkvw_bf, bufA, qkv_b, nullptr,
                                               (void*)qkvbuf, 768);
  // 3) windowed attention -> A^T swizzled (bufA)
  attn_kernel<<<dim3(144, 8), 256, 0, stream>>>(qkvbuf, relb, nm, bufA);
  // 4) out conv + residual -> x1 f32 (bufB)
  gemm_nt<1><<<dim3(450, 2), 256, 0, stream>>>(outw_bf, bufA, out_b, src,
                                               (void*)x1, 256);
  // 5) LN2 -> X^T swizzled (bufA)
  ln_kernel<<<225, 256, 0, stream>>>(x1, n2_g, n2_b, bufA);
  // 6) fused FFN + residual + final mask -> d_out
  ffn_kernel<<<900, 256, 0, stream>>>(bufA, w1_bf, w2_bf, lin1_b, lin2_b, x1, nm,
                                      (float*)d_out);
}

// Round 3
// 810.673 us; speedup vs baseline: 7.4062x; 3.0055x over previous
//
#include <hip/hip_runtime.h>
#include <hip/hip_bf16.h>
#include <math.h>

typedef unsigned short u16;
typedef unsigned int   u32;
typedef __attribute__((ext_vector_type(8))) short bf16x8;
typedef __attribute__((ext_vector_type(4))) float f32x4;
typedef __attribute__((ext_vector_type(16))) float f32x16;

#define NSIDE  240
#define NPIX   57600
#define DMODEL 256
#define NHEAD  8
#define HDIM   32
#define LWIN   20
#define NWIN   12
#define FF     400
#define DFFN   2048
#define BTAB   39   // 2*LW-1
#define LOG2E  1.4426950408889634f
#define QSCALE 0.2550773933046f   // 32^-0.5 * log2(e)

// ---- ws layout (bytes) ----
#define OFF_QKVW  0u           // 768*256 bf16 (swizzled)
#define OFF_OUTW  393216u      // 256*256 bf16 (swizzled)
#define OFF_W1    524288u      // 2048*256 bf16 (plain)
#define OFF_W2    1572864u     // 256*2048 bf16 (plain)
#define OFF_FLAG  2621440u
#define OFF_WANY  2621504u     // 144 int
#define OFF_WMASK 2622080u     // 144*13 u32
#define OFF_NM    2629568u     // 57600 B
#define OFF_A     2687488u     // 57600*256 bf16 (X^T swizzled: ln1out/attnout/ln2out)
#define OFF_B     32178688u    // qkvT bf16 [NPIX][768]; later x1 f32 [256][NPIX]
// bias table (bf16, C-frag order, 2.77MB) lives in d_out's tail; ffn overwrites d_out.

__device__ __forceinline__ float bf2f(u16 u){
  union { float f; u32 i; } v; v.i = ((u32)u) << 16; return v.f;
}
__device__ __forceinline__ float bflo(u32 u){
  union { float f; u32 i; } v; v.i = u << 16; return v.f;
}
__device__ __forceinline__ float bfhi(u32 u){
  union { float f; u32 i; } v; v.i = u & 0xffff0000u; return v.f;
}
__device__ __forceinline__ u16 f2bf(float f){
  union { float f; u32 i; } v; v.f = f;
  u32 r = v.i + 0x7fffu + ((v.i >> 16) & 1u);
  return (u16)(r >> 16);
}
__device__ __forceinline__ u32 pkbf(float a, float b){
  float2 f2; f2.x = a; f2.y = b;
  __hip_bfloat162 h = __float22bfloat162_rn(f2);
  union { __hip_bfloat162 h; u32 u; } c; c.h = h; return c.u;
}
__device__ __forceinline__ void gload16(const void* g, void* l){
  __builtin_amdgcn_global_load_lds((const __attribute__((address_space(1))) u32*)g,
                                   (__attribute__((address_space(3))) u32*)l, 16, 0, 0);
}

// ---------------- prep: f32 -> bf16 weight converts ----------------
__global__ void cvt_kernel(const float* __restrict__ in, u16* __restrict__ out, int n){
  int i = blockIdx.x * 256 + threadIdx.x;
  if (i < n) out[i] = f2bf(in[i]);
}
// swizzled variant for K=256 row-major weights: elem k stored at k ^ ((m&7)<<3)
__global__ void cvt_sw_kernel(const float* __restrict__ in, u16* __restrict__ out, int n){
  int i = blockIdx.x * 256 + threadIdx.x;
  if (i >= n) return;
  int m = i >> 8, k = i & 255;
  out[(m << 8) + (k ^ ((m & 7) << 3))] = f2bf(in[i]);
}

// ---------------- mask dtype detect + normalize ----------------
__global__ void detect_mask(const unsigned char* __restrict__ m, int* __restrict__ flag){
  __shared__ int sc;
  if (threadIdx.x == 0) sc = 0;
  __syncthreads();
  int local = 0;
  for (int p = threadIdx.x; p < NPIX; p += blockDim.x){
    int i = p / NSIDE, j = p - i * NSIDE;
    int pt = j * NSIDE + i;
    int a = (m[p] != 0), b = (m[pt] != 0);
    local += (a != b);
  }
  atomicAdd(&sc, local);
  __syncthreads();
  if (threadIdx.x == 0) *flag = (sc > 0) ? 1 : 0;
}
__global__ void norm_mask(const void* __restrict__ m, const int* __restrict__ flag,
                          unsigned char* __restrict__ nm){
  int p = blockIdx.x * 256 + threadIdx.x;
  int v;
  if (*flag) v = (((const int*)m)[p] != 0);
  else       v = (((const unsigned char*)m)[p] != 0);
  nm[p] = (unsigned char)v;
}

// ---------------- per-window mask bitmaps (with full-window reset) ----------------
__global__ void wmask_kernel(const unsigned char* __restrict__ nm,
                             u32* __restrict__ wmask, int* __restrict__ wany){
  int w = blockIdx.x;
  int wi = w / NWIN, wj = w % NWIN;
  __shared__ u32 bits[13];
  __shared__ int cnt;
  int t = threadIdx.x;
  if (t < 13) bits[t] = 0;
  if (t == 0) cnt = 0;
  __syncthreads();
  if (t < FF){
    int pj = (wi * LWIN + t / LWIN) * NSIDE + wj * LWIN + (t % LWIN);
    if (nm[pj]){ atomicOr(&bits[t >> 5], 1u << (t & 31)); atomicAdd(&cnt, 1); }
  }
  __syncthreads();
  int full = (cnt == FF);
  if (t < 13) wmask[w * 13 + t] = full ? 0u : bits[t];
  if (t == 0) wany[w] = (cnt > 0 && !full) ? 1 : 0;
}

// ---------------- bias table in C-fragment order (bf16, exp2 domain) ----------------
// biasT[(h*169 + it*13 + jt)*64*16 + lane*16 + r] = log2e*rel[i][j][h], or -1e30 for j>=400
__global__ void bias_prep(const float* __restrict__ relb, u16* __restrict__ biasT){
  int tile = blockIdx.x;       // it*13+jt
  int h = blockIdx.y;
  int it = tile / 13, jt = tile % 13;
  int t = threadIdx.x;
  int lane = t & 63, rq = t >> 6;
  int lane31 = lane & 31, hi = lane >> 5;
  int i = it * 32 + lane31; if (i > FF - 1) i = FF - 1;
  int xi = i / LWIN, yi = i % LWIN;
  u16* dst = biasT + ((size_t)(h * 169 + tile) * 64 + lane) * 16;
  #pragma unroll
  for (int q = 0; q < 4; q++){
    int r = rq * 4 + q;
    int j = jt * 32 + (r & 3) + 8 * (r >> 2) + 4 * hi;
    float v;
    if (j < FF){
      int xj = j / LWIN, yj = j % LWIN;
      int r0 = xj - xi; if (r0 < 0) r0 += BTAB;
      int r1 = yj - yi; if (r1 < 0) r1 += BTAB;
      v = LOG2E * relb[(r0 * BTAB + r1) * NHEAD + h];
    } else v = -1e30f;
    dst[r] = f2bf(v);
  }
}

// ---------------- LayerNorm over channels -> X^T [NPIX][256] bf16, swizzled ----------------
__global__ __launch_bounds__(256) void ln_kernel(const float* __restrict__ x,
                          const float* __restrict__ g, const float* __restrict__ b,
                          u16* __restrict__ out){
  int p = blockIdx.x * 256 + threadIdx.x;
  float s = 0.f, s2 = 0.f;
  for (int c = 0; c < DMODEL; c++){
    float v = x[c * NPIX + p];
    s += v; s2 += v * v;
  }
  float m = s * (1.f / DMODEL);
  float var = s2 * (1.f / DMODEL) - m * m;
  float inv = rsqrtf(var + 1e-5f);
  int sw = (p & 7) << 3;
  u16* orow = out + (size_t)p * DMODEL;
  for (int c = 0; c < DMODEL; c += 2){
    float v0 = (x[c * NPIX + p] - m) * inv * g[c] + b[c];
    float v1 = (x[(c + 1) * NPIX + p] - m) * inv * g[c + 1] + b[c + 1];
    u32 pk = (u32)f2bf(v0) | ((u32)f2bf(v1) << 16);
    *(u32*)&orow[c ^ sw] = pk;
  }
}

// ---------------- MFMA GEMM: C = W[M][256] * Xt[NPIX][256]^T ----------------
// EPI 0: +bias -> bf16 [M][NPIX]; EPI 1: +bias+res -> f32 [M][NPIX];
// EPI 2: +bias, q-scale (m<256), -> bf16 TRANSPOSED [NPIX][768]
template<int EPI>
__global__ __launch_bounds__(256) void gemm_nt(const u16* __restrict__ W,
    const u16* __restrict__ Xt, const float* __restrict__ bias,
    const float* __restrict__ res, void* __restrict__ outp, int M){
  __shared__ u16 Ws[128 * 64];
  __shared__ u16 Xs[128 * 64];
  int t = threadIdx.x, wv = t >> 6, ln = t & 63;
  int n0 = blockIdx.x * 128, m0 = blockIdx.y * 128;
  int wr = wv >> 1, wc = wv & 1;
  f32x4 acc[4][4];
  #pragma unroll
  for (int r = 0; r < 4; r++)
    #pragma unroll
    for (int c = 0; c < 4; c++) acc[r][c] = (f32x4)0.f;
  const char* Wb = (const char*)W;
  const char* Xb = (const char*)Xt;
  for (int k0 = 0; k0 < 256; k0 += 64){
    #pragma unroll
    for (int i = 0; i < 4; i++){
      int wb = (wv * 4 + i) * 1024;
      int q  = wb + ln * 16;
      int row = q >> 7, off = q & 127;
      gload16(Wb + (size_t)(m0 + row) * 512 + k0 * 2 + off, (char*)Ws + wb);
      gload16(Xb + (size_t)(n0 + row) * 512 + k0 * 2 + off, (char*)Xs + wb);
    }
    __syncthreads();
    #pragma unroll
    for (int kk = 0; kk < 64; kk += 32){
      int kidx = kk + (ln >> 4) * 8;
      int swz = (ln & 7) << 3;
      bf16x8 af[4], bfr[4];
      #pragma unroll
      for (int r = 0; r < 4; r++){
        int row = wr * 64 + r * 16 + (ln & 15);
        af[r] = *(const bf16x8*)&Ws[row * 64 + (kidx ^ swz)];
      }
      #pragma unroll
      for (int c = 0; c < 4; c++){
        int row = wc * 64 + c * 16 + (ln & 15);
        bfr[c] = *(const bf16x8*)&Xs[row * 64 + (kidx ^ swz)];
      }
      #pragma unroll
      for (int r = 0; r < 4; r++)
        #pragma unroll
        for (int c = 0; c < 4; c++)
          acc[r][c] = __builtin_amdgcn_mfma_f32_16x16x32_bf16(af[r], bfr[c], acc[r][c], 0, 0, 0);
    }
    __syncthreads();
  }
  #pragma unroll
  for (int r = 0; r < 4; r++){
    int mo0 = m0 + wr * 64 + r * 16 + (ln >> 4) * 4;
    f32x4 bv = *(const f32x4*)&bias[mo0];
    #pragma unroll
    for (int c = 0; c < 4; c++){
      int no = n0 + wc * 64 + c * 16 + (ln & 15);
      if (EPI == 2){
        float sc = (mo0 < 256) ? QSCALE : 1.0f;
        u32 lo  = pkbf((acc[r][c][0] + bv[0]) * sc, (acc[r][c][1] + bv[1]) * sc);
        u32 hi2 = pkbf((acc[r][c][2] + bv[2]) * sc, (acc[r][c][3] + bv[3]) * sc);
        u32* op = (u32*)((u16*)outp + (size_t)no * 768 + mo0);
        op[0] = lo; op[1] = hi2;
      } else {
        #pragma unroll
        for (int q = 0; q < 4; q++){
          float v = acc[r][c][q] + bv[q];
          size_t oi = (size_t)(mo0 + q) * NPIX + no;
          if (EPI == 0) ((u16*)outp)[oi] = f2bf(v);
          else          ((float*)outp)[oi] = v + res[oi];
        }
      }
    }
  }
}

// ---------------- MFMA windowed attention ----------------
// block = (window, head), 4 waves; swapped QK^T (S^T = K·Q, C-init = bias frags);
// online softmax per lane (col i = lane&31); PV: O^T = V·P^T.
__global__ __launch_bounds__(256) void attn_kernel(
    const u16* __restrict__ qkvT, const u16* __restrict__ biasT,
    const u32* __restrict__ wmask, const int* __restrict__ wany,
    u16* __restrict__ out)
{
  __shared__ u16 Ks[416 * 40];   // [j][40] rows: 64B K data + 16B pad (bank-stride 20)
  __shared__ u16 Vs[32 * 424];   // [d][424]: 800B data + pad (bank-stride 20)
  int w = blockIdx.x, h = blockIdx.y;
  int wi = w / NWIN, wj = w % NWIN;
  int t = threadIdx.x;
  // ---- stage K (zero-padded to 416 rows) and V (transposed) ----
  for (int it = 0; it < 7; it++){
    int idx = t + it * 256;
    int j = idx >> 2, c = idx & 3;
    if (j >= 416) break;
    uint4 gv = make_uint4(0, 0, 0, 0);
    if (j < FF){
      int pj = (wi * LWIN + j / LWIN) * NSIDE + wj * LWIN + (j % LWIN);
      gv = *(const uint4*)&qkvT[(size_t)pj * 768 + 256 + h * 32 + c * 8];
      uint4 vv = *(const uint4*)&qkvT[(size_t)pj * 768 + 512 + h * 32 + c * 8];
      u32 vw[4] = {vv.x, vv.y, vv.z, vv.w};
      int d0 = c * 8;
      #pragma unroll
      for (int q = 0; q < 4; q++){
        Vs[(d0 + 2 * q) * 424 + j]     = (u16)vw[q];
        Vs[(d0 + 2 * q + 1) * 424 + j] = (u16)(vw[q] >> 16);
      }
    }
    *(uint4*)&Ks[j * 40 + c * 8] = gv;
  }
  __syncthreads();
  int wv = t >> 6, ln = t & 63;
  int lane31 = ln & 31, hi = ln >> 5;
  int anym = wany[w];
  for (int it8 = wv; it8 < 13; it8 += 4){
    int i = it8 * 32 + lane31;
    int ic = i < FF ? i : FF - 1;
    int pi = (wi * LWIN + ic / LWIN) * NSIDE + wj * LWIN + (ic % LWIN);
    bf16x8 qf0 = *(const bf16x8*)&qkvT[(size_t)pi * 768 + h * 32 + hi * 8];
    bf16x8 qf1 = *(const bf16x8*)&qkvT[(size_t)pi * 768 + h * 32 + 16 + hi * 8];
    float m = -3e38f, lsum = 0.f;
    f32x16 o;
    #pragma unroll
    for (int r = 0; r < 16; r++) o[r] = 0.f;
    const u16* btb = biasT + ((size_t)(h * 169 + it8 * 13) * 64 + ln) * 16;
    for (int jt = 0; jt < 13; jt++){
      // C-init = bias fragment (bf16 -> f32)
      const uint4* bt = (const uint4*)(btb + (size_t)jt * 1024);
      uint4 bw0 = bt[0], bw1 = bt[1];
      u32 bwv[8] = {bw0.x, bw0.y, bw0.z, bw0.w, bw1.x, bw1.y, bw1.z, bw1.w};
      f32x16 acc;
      #pragma unroll
      for (int e = 0; e < 8; e++){ acc[2 * e] = bflo(bwv[e]); acc[2 * e + 1] = bfhi(bwv[e]); }
      // S^T = K . Q + bias
      bf16x8 kf0 = *(const bf16x8*)&Ks[(jt * 32 + lane31) * 40 + hi * 8];
      bf16x8 kf1 = *(const bf16x8*)&Ks[(jt * 32 + lane31) * 40 + 16 + hi * 8];
      acc = __builtin_amdgcn_mfma_f32_32x32x16_bf16(kf0, qf0, acc, 0, 0, 0);
      acc = __builtin_amdgcn_mfma_f32_32x32x16_bf16(kf1, qf1, acc, 0, 0, 0);
      if (anym){
        u32 mb = wmask[w * 13 + jt];
        if (mb){
          #pragma unroll
          for (int r = 0; r < 16; r++){
            int jb = (r & 3) + 8 * (r >> 2) + 4 * hi;
            if ((mb >> jb) & 1) acc[r] = -1e30f;
          }
        }
      }
      // online softmax (exp2 domain); partner lane (xor 32) shares column i
      float tm = acc[0];
      #pragma unroll
      for (int r = 1; r < 16; r++) tm = fmaxf(tm, acc[r]);
      tm = fmaxf(tm, __shfl_xor(tm, 32));
      if (tm > m){
        float sc = exp2f(m - tm);
        lsum *= sc;
        #pragma unroll
        for (int r = 0; r < 16; r++) o[r] *= sc;
        m = tm;
      }
      float p[16];
      float ls = 0.f;
      #pragma unroll
      for (int r = 0; r < 16; r++){ p[r] = exp2f(acc[r] - m); ls += p[r]; }
      lsum += ls;
      // pack P -> B-frag (col i, k=j) via cvt_pk + half-exchange
      u32 x01 = pkbf(p[0], p[1]), x23 = pkbf(p[2], p[3]);
      u32 x45 = pkbf(p[4], p[5]), x67 = pkbf(p[6], p[7]);
      u32 y01 = __shfl_xor(x01, 32), y23 = __shfl_xor(x23, 32);
      u32 y45 = __shfl_xor(x45, 32), y67 = __shfl_xor(x67, 32);
      union { u32 u[4]; bf16x8 v; } f0;
      f0.u[0] = hi ? y45 : x01; f0.u[1] = hi ? y67 : x23;
      f0.u[2] = hi ? x45 : y01; f0.u[3] = hi ? x67 : y23;
      bf16x8 vf0 = *(const bf16x8*)&Vs[lane31 * 424 + jt * 32 + hi * 8];
      o = __builtin_amdgcn_mfma_f32_32x32x16_bf16(vf0, f0.v, o, 0, 0, 0);
      if (jt < 12){
        u32 x89 = pkbf(p[8], p[9]),   xab = pkbf(p[10], p[11]);
        u32 xcd = pkbf(p[12], p[13]), xef = pkbf(p[14], p[15]);
        u32 y89 = __shfl_xor(x89, 32), yab = __shfl_xor(xab, 32);
        u32 ycd = __shfl_xor(xcd, 32), yef = __shfl_xor(xef, 32);
        union { u32 u[4]; bf16x8 v; } f1;
        f1.u[0] = hi ? ycd : x89; f1.u[1] = hi ? yef : xab;
        f1.u[2] = hi ? xcd : y89; f1.u[3] = hi ? xef : yab;
        bf16x8 vf1 = *(const bf16x8*)&Vs[lane31 * 424 + jt * 32 + 16 + hi * 8];
        o = __builtin_amdgcn_mfma_f32_32x32x16_bf16(vf1, f1.v, o, 0, 0, 0);
      }
    }
    lsum += __shfl_xor(lsum, 32);
    if (i < FF){
      float linv = 1.f / lsum;
      int sw = (pi & 7) << 3;
      u16* orow = out + (size_t)pi * DMODEL;
      #pragma unroll
      for (int g = 0; g < 4; g++){
        int ch0 = h * 32 + g * 8 + hi * 4;
        u32 lo  = pkbf(o[g * 4 + 0] * linv, o[g * 4 + 1] * linv);
        u32 hi2 = pkbf(o[g * 4 + 2] * linv, o[g * 4 + 3] * linv);
        *(u32*)&orow[(ch0 ^ sw)]     = lo;
        *(u32*)&orow[(ch0 ^ sw) + 2] = hi2;
      }
    }
  }
}

// ---------------- fused FFN (MFMA) ----------------
__global__ __launch_bounds__(256) void ffn_kernel(const u16* __restrict__ xt,
    const u16* __restrict__ w1, const u16* __restrict__ w2,
    const float* __restrict__ b1, const float* __restrict__ b2,
    const float* __restrict__ resid, const unsigned char* __restrict__ pmask,
    float* __restrict__ out){
  __shared__ u16 Xs[64 * 256];
  __shared__ u16 Hs[64 * 72];
  int t = threadIdx.x, wv = t >> 6, ln = t & 63;
  int p0 = blockIdx.x * 64;
  const char* xb = (const char*)xt + (size_t)p0 * 512;
  #pragma unroll
  for (int i = 0; i < 8; i++){
    int wb = (wv * 8 + i) * 1024;
    gload16(xb + wb + ln * 16, (char*)Xs + wb);
  }
  f32x4 acc[4][4];
  #pragma unroll
  for (int r = 0; r < 4; r++)
    #pragma unroll
    for (int c = 0; c < 4; c++) acc[r][c] = (f32x4)0.f;
  int swx = (ln & 7) << 3;
  __syncthreads();
  for (int fc = 0; fc < DFFN; fc += 64){
    f32x4 ha[4];
    #pragma unroll
    for (int c = 0; c < 4; c++) ha[c] = (f32x4)0.f;
    const u16* w1r = w1 + (size_t)(fc + wv * 16 + (ln & 15)) * 256 + (ln >> 4) * 8;
    #pragma unroll
    for (int k0 = 0; k0 < 256; k0 += 32){
      bf16x8 aw = *(const bf16x8*)&w1r[k0];
      #pragma unroll
      for (int c = 0; c < 4; c++){
        int p = c * 16 + (ln & 15);
        bf16x8 bx = *(const bf16x8*)&Xs[p * 256 + ((k0 + (ln >> 4) * 8) ^ swx)];
        ha[c] = __builtin_amdgcn_mfma_f32_16x16x32_bf16(aw, bx, ha[c], 0, 0, 0);
      }
    }
    int f0 = wv * 16 + (ln >> 4) * 4;
    f32x4 bv1 = *(const f32x4*)&b1[fc + f0];
    #pragma unroll
    for (int c = 0; c < 4; c++){
      int p = c * 16 + (ln & 15);
      uint2 pk;
      pk.x = pkbf(fmaxf(ha[c][0] + bv1[0], 0.f), fmaxf(ha[c][1] + bv1[1], 0.f));
      pk.y = pkbf(fmaxf(ha[c][2] + bv1[2], 0.f), fmaxf(ha[c][3] + bv1[3], 0.f));
      *(uint2*)&Hs[p * 72 + f0] = pk;
    }
    __syncthreads();
    #pragma unroll
    for (int kk = 0; kk < 64; kk += 32){
      int fi = kk + (ln >> 4) * 8;
      bf16x8 a2[4], hb[4];
      #pragma unroll
      for (int r = 0; r < 4; r++)
        a2[r] = *(const bf16x8*)&w2[(size_t)(wv * 64 + r * 16 + (ln & 15)) * 2048 + fc + fi];
      #pragma unroll
      for (int c = 0; c < 4; c++)
        hb[c] = *(const bf16x8*)&Hs[(c * 16 + (ln & 15)) * 72 + fi];
      #pragma unroll
      for (int r = 0; r < 4; r++)
        #pragma unroll
        for (int c = 0; c < 4; c++)
          acc[r][c] = __builtin_amdgcn_mfma_f32_16x16x32_bf16(a2[r], hb[c], acc[r][c], 0, 0, 0);
    }
    __syncthreads();
  }
  #pragma unroll
  for (int r = 0; r < 4; r++){
    int o0 = wv * 64 + r * 16 + (ln >> 4) * 4;
    f32x4 bv = *(const f32x4*)&b2[o0];
    #pragma unroll
    for (int c = 0; c < 4; c++){
      int p = p0 + c * 16 + (ln & 15);
      int msk = pmask[p];
      #pragma unroll
      for (int q = 0; q < 4; q++){
        size_t oi = (size_t)(o0 + q) * NPIX + p;
        float v = acc[r][c][q] + bv[q] + resid[oi];
        out[oi] = msk ? 0.f : v;
      }
    }
  }
}

extern "C" void kernel_launch(void* const* d_in, const int* in_sizes, int n_in,
                              void* d_out, int out_size, void* d_ws, size_t ws_size,
                              hipStream_t stream){
  const float* src    = (const float*)d_in[0];
  const void*  pmraw  = d_in[1];
  const float* qkv_w  = (const float*)d_in[2];
  const float* qkv_b  = (const float*)d_in[3];
  const float* out_w  = (const float*)d_in[4];
  const float* out_b  = (const float*)d_in[5];
  const float* lin1_w = (const float*)d_in[6];
  const float* lin1_b = (const float*)d_in[7];
  const float* lin2_w = (const float*)d_in[8];
  const float* lin2_b = (const float*)d_in[9];
  const float* n1_g   = (const float*)d_in[10];
  const float* n1_b   = (const float*)d_in[11];
  const float* n2_g   = (const float*)d_in[12];
  const float* n2_b   = (const float*)d_in[13];
  const float* relb   = (const float*)d_in[14];

  char* ws = (char*)d_ws;
  u16* qkvw_bf = (u16*)(ws + OFF_QKVW);
  u16* outw_bf = (u16*)(ws + OFF_OUTW);
  u16* w1_bf   = (u16*)(ws + OFF_W1);
  u16* w2_bf   = (u16*)(ws + OFF_W2);
  int* flag    = (int*)(ws + OFF_FLAG);
  int* wany    = (int*)(ws + OFF_WANY);
  u32* wmaskp  = (u32*)(ws + OFF_WMASK);
  unsigned char* nm = (unsigned char*)(ws + OFF_NM);
  u16* bufA    = (u16*)(ws + OFF_A);   // X^T swizzled: ln1out -> attnout -> ln2out
  u16* qkvT    = (u16*)(ws + OFF_B);   // qkv bf16 [NPIX][768]
  float* x1    = (float*)(ws + OFF_B); // residual stream f32 (qkvT dead after attn)
  u16* biasT   = (u16*)d_out;          // bias table lives in d_out; ffn overwrites later

  // prep
  cvt_sw_kernel<<<768,  256, 0, stream>>>(qkv_w,  qkvw_bf, 768 * 256);
  cvt_sw_kernel<<<256,  256, 0, stream>>>(out_w,  outw_bf, 256 * 256);
  cvt_kernel<<<2048, 256, 0, stream>>>(lin1_w, w1_bf, 2048 * 256);
  cvt_kernel<<<2048, 256, 0, stream>>>(lin2_w, w2_bf, 256 * 2048);
  detect_mask<<<1, 256, 0, stream>>>((const unsigned char*)pmraw, flag);
  norm_mask<<<225, 256, 0, stream>>>(pmraw, flag, nm);
  wmask_kernel<<<144, 512, 0, stream>>>(nm, wmaskp, wany);
  bias_prep<<<dim3(169, 8), 256, 0, stream>>>(relb, biasT);

  // 1) LN1 -> X^T swizzled (bufA)
  ln_kernel<<<225, 256, 0, stream>>>(src, n1_g, n1_b, bufA);
  // 2) qkvT = (W_qkv . X + b)^T -> [NPIX][768] bf16, q pre-scaled
  gemm_nt<2><<<dim3(450, 6), 256, 0, stream>>>(qkvw_bf, bufA, qkv_b, nullptr,
                                               (void*)qkvT, 768);
  // 3) MFMA windowed attention -> A^T swizzled (bufA)
  attn_kernel<<<dim3(144, 8), 256, 0, stream>>>(qkvT, biasT, wmaskp, wany, bufA);
  // 4) out conv + residual -> x1 f32 (region B, qkvT dead)
  gemm_nt<1><<<dim3(450, 2), 256, 0, stream>>>(outw_bf, bufA, out_b, src,
                                               (void*)x1, 256);
  // 5) LN2 -> X^T swizzled (bufA)
  ln_kernel<<<225, 256, 0, stream>>>(x1, n2_g, n2_b, bufA);
  // 6) fused FFN + residual + final mask -> d_out (overwrites biasT region)
  ffn_kernel<<<900, 256, 0, stream>>>(bufA, w1_bf, w2_bf, lin1_b, lin2_b, x1, nm,
                                      (float*)d_out);
}